// Round 8
// baseline (58.094 us; speedup 1.0000x reference)
//
#include <hip/hip_runtime.h>
#include <hip/hip_bf16.h>
#include <stdint.h>

#define BN 32
#define CIN 64
#define COUTC 64
#define TT 6
#define VV 512
#define NEG_FILL -1000.0f
#define SLOPE 0.2f

using bf16x8 = __attribute__((ext_vector_type(8))) short;
using bf16x4 = __attribute__((ext_vector_type(4))) short;
using f32x4  = __attribute__((ext_vector_type(4))) float;

static __device__ __forceinline__ unsigned short f2bf(float f) {
    union { float f; unsigned int i; } x; x.f = f;
    unsigned int r = x.i + 0x7FFFu + ((x.i >> 16) & 1u);
    return (unsigned short)(r >> 16);
}

#define GLD16(gp, lp) __builtin_amdgcn_global_load_lds( \
    (const __attribute__((address_space(1))) void*)(gp), \
    (__attribute__((address_space(3))) void*)(lp), 16, 0, 0)

// ---------------- k1: xc = W·x + b via MFMA (bf16 inputs, f32 accum)
__global__ __launch_bounds__(256) void k1_conv(const float* __restrict__ x,
                                               const float* __restrict__ W,
                                               const float* __restrict__ bias,
                                               const float* __restrict__ l1w,
                                               const float* __restrict__ l2w,
                                               unsigned short* __restrict__ xcb,
                                               float* __restrict__ spartS,
                                               float* __restrict__ spartD) {
    __shared__ __align__(16) unsigned short Ws[64 * 64];    // 8 KB  [o][i] octet-swizzled
    __shared__ __align__(16) unsigned short Bs[128 * 64];   // 16 KB [v][i]; reused for out
    int bid = blockIdx.x;                  // (n*T + t)*4 + vq
    int vq = bid & 3; int nt = bid >> 2; int t = nt % TT; int n = nt / TT;
    int tid = threadIdx.x; int wv = tid >> 6, ln = tid & 63;
    int v0 = vq * 128;

    {
        int o = tid >> 2, i16 = (tid & 3) * 16;
        const float* wr_ = W + o * CIN + i16;
        f32x4 a = *(const f32x4*)&wr_[0], b = *(const f32x4*)&wr_[4];
        f32x4 c = *(const f32x4*)&wr_[8], d = *(const f32x4*)&wr_[12];
        bf16x8 p0, p1;
        #pragma unroll
        for (int e = 0; e < 4; ++e) {
            p0[e] = (short)f2bf(a[e]); p0[e + 4] = (short)f2bf(b[e]);
            p1[e] = (short)f2bf(c[e]); p1[e + 4] = (short)f2bf(d[e]);
        }
        int j0 = i16 >> 3;
        *(bf16x8*)&Ws[o * 64 + ((j0 ^ (o & 7)) << 3)]       = p0;
        *(bf16x8*)&Ws[o * 64 + (((j0 + 1) ^ (o & 7)) << 3)] = p1;
    }
    const float* xg = x + ((size_t)(n * CIN) * TT + t) * VV + v0;
    {
        int v4 = (tid & 31) * 4;
        int ig0 = tid >> 5;
        #pragma unroll
        for (int g = 0; g < 2; ++g) {
            int i4 = (ig0 + g * 8) * 4;
            f32x4 r0 = __builtin_nontemporal_load((const f32x4*)&xg[(size_t)(i4 + 0) * TT * VV + v4]);
            f32x4 r1 = __builtin_nontemporal_load((const f32x4*)&xg[(size_t)(i4 + 1) * TT * VV + v4]);
            f32x4 r2 = __builtin_nontemporal_load((const f32x4*)&xg[(size_t)(i4 + 2) * TT * VV + v4]);
            f32x4 r3 = __builtin_nontemporal_load((const f32x4*)&xg[(size_t)(i4 + 3) * TT * VV + v4]);
            int j = i4 >> 3, h = (i4 >> 2) & 1;
            #pragma unroll
            for (int c = 0; c < 4; ++c) {
                int v = v4 + c;
                bf16x4 col;
                col[0] = (short)f2bf(r0[c]); col[1] = (short)f2bf(r1[c]);
                col[2] = (short)f2bf(r2[c]); col[3] = (short)f2bf(r3[c]);
                *(bf16x4*)&Bs[v * 64 + ((j ^ (v & 7)) << 3) + h * 4] = col;
            }
        }
    }
    __syncthreads();

    int fr = ln & 15, fkq = ln >> 4;
    f32x4 acc[4][2] = {};
    #pragma unroll
    for (int ks = 0; ks < 2; ++ks) {
        bf16x8 af[4], bfv[2];
        int oct = fkq + ks * 4;
        #pragma unroll
        for (int mi = 0; mi < 4; ++mi) {
            int o = mi * 16 + fr;
            af[mi] = *(const bf16x8*)&Ws[o * 64 + ((oct ^ (o & 7)) << 3)];
        }
        #pragma unroll
        for (int ni = 0; ni < 2; ++ni) {
            int v = wv * 32 + ni * 16 + fr;
            bfv[ni] = *(const bf16x8*)&Bs[v * 64 + ((oct ^ (v & 7)) << 3)];
        }
        #pragma unroll
        for (int mi = 0; mi < 4; ++mi)
            #pragma unroll
            for (int ni = 0; ni < 2; ++ni)
                acc[mi][ni] = __builtin_amdgcn_mfma_f32_16x16x32_bf16(af[mi], bfv[ni], acc[mi][ni], 0, 0, 0);
    }
    __syncthreads();

    float l2wt = l2w[t];
    float partS[2] = {0.f, 0.f}, partD[2] = {0.f, 0.f};
    #pragma unroll
    for (int mi = 0; mi < 4; ++mi)
        #pragma unroll
        for (int q = 0; q < 4; ++q) {
            int o = mi * 16 + (ln >> 4) * 4 + q;
            float bv = bias[o];
            float wS = l1w[o], wD = l1w[COUTC + o];
            #pragma unroll
            for (int ni = 0; ni < 2; ++ni) {
                float z = acc[mi][ni][q] + bv;
                partS[ni] += wS * z;
                partD[ni] += wD * z;
                int vloc = wv * 32 + ni * 16 + fr;
                int vsw = (((vloc >> 3) ^ (o & 15)) << 3) | (vloc & 7);
                Bs[o * 128 + vsw] = f2bf(z);
            }
        }
    #pragma unroll
    for (int ni = 0; ni < 2; ++ni) {
        float sS = partS[ni], sD = partD[ni];
        sS += __shfl_xor(sS, 16); sS += __shfl_xor(sS, 32);
        sD += __shfl_xor(sD, 16); sD += __shfl_xor(sD, 32);
        if (ln < 16) {
            int v = v0 + wv * 32 + ni * 16 + ln;
            size_t si_ = ((size_t)n * TT + t) * VV + v;
            spartS[si_] = l2wt * sS;
            spartD[si_] = l2wt * sD;
        }
    }
    __syncthreads();

    {
        int o = tid >> 2, c32 = (tid & 3) * 32;
        size_t base = ((size_t)(n * COUTC + o) * TT + t) * VV + v0 + c32;
        #pragma unroll
        for (int q = 0; q < 4; ++q) {
            int oct = (tid & 3) * 4 + q;
            bf16x8 val = *(const bf16x8*)&Bs[o * 128 + ((oct ^ (o & 15)) << 3)];
            *(bf16x8*)&xcb[base + q * 8] = val;
        }
    }
}

// ---------------- k2: softmax rows -> a4 f32 (d_out, NT) + fused LDS transpose -> a4t bf16
__global__ __launch_bounds__(512) void k2_softmax(const float* __restrict__ A,
                                                  const float* __restrict__ spartS,
                                                  const float* __restrict__ spartD,
                                                  const float* __restrict__ l1w,
                                                  const float* __restrict__ l1b_,
                                                  const float* __restrict__ l2b_,
                                                  float* __restrict__ a4out,
                                                  unsigned short* __restrict__ a4t) {
    __shared__ unsigned short tile[32][520];   // 32 rows x 512 (+8 pad), 32.5 KB
    __shared__ float si_loc[32];
    int blk = blockIdx.x;                 // n*16 + ib
    int n = blk >> 4; int i0 = (blk & 15) * 32;
    int wv = threadIdx.x >> 6, lane = threadIdx.x & 63;

    float sws = 0.f, swd = 0.f;
    for (int c = 0; c < COUTC; ++c) { sws += l1w[c]; swd += l1w[COUTC + c]; }
    float l2b = l2b_[0], l1b = l1b_[0];

    if (threadIdx.x < 32) {
        float s = 0.f;
        #pragma unroll
        for (int t = 0; t < TT; ++t)
            s += spartS[((size_t)n * TT + t) * VV + i0 + threadIdx.x];
        si_loc[threadIdx.x] = s + l2b * sws;
    }
    f32x4 sj0 = {0.f, 0.f, 0.f, 0.f}, sj1 = {0.f, 0.f, 0.f, 0.f};
    #pragma unroll
    for (int t = 0; t < TT; ++t) {
        const float* p = &spartD[((size_t)n * TT + t) * VV + lane * 8];
        f32x4 d0 = *(const f32x4*)&p[0];
        f32x4 d1 = *(const f32x4*)&p[4];
        #pragma unroll
        for (int e = 0; e < 4; ++e) { sj0[e] += d0[e]; sj1[e] += d1[e]; }
    }
    float cst = l2b * swd + l1b;
    #pragma unroll
    for (int e = 0; e < 4; ++e) { sj0[e] += cst; sj1[e] += cst; }
    __syncthreads();

    for (int it = 0; it < 4; ++it) {
        int il = it * 8 + wv;             // local row 0..31
        int i  = i0 + il;
        int row = n * VV + i;
        float s_i = si_loc[il];
        const float* mrow = A + ((size_t)n * 8 + 7) * VV * VV + (size_t)i * VV;
        f32x4 m0 = __builtin_nontemporal_load((const f32x4*)&mrow[lane * 8]);
        f32x4 m1 = __builtin_nontemporal_load((const f32x4*)&mrow[lane * 8 + 4]);

        float sc[8];
        float mx = -1e30f;
        #pragma unroll
        for (int e = 0; e < 8; ++e) {
            float mk = (e < 4) ? m0[e] : m1[e - 4];
            float s  = s_i + ((e < 4) ? sj0[e] : sj1[e - 4]);
            s = (s >= 0.f) ? s : SLOPE * s;
            s = (mk == 0.f) ? NEG_FILL : s;
            sc[e] = s;
            mx = fmaxf(mx, s);
        }
        #pragma unroll
        for (int off = 32; off; off >>= 1) mx = fmaxf(mx, __shfl_xor(mx, off));
        float sum = 0.f;
        #pragma unroll
        for (int e = 0; e < 8; ++e) { sc[e] = __expf(sc[e] - mx); sum += sc[e]; }
        #pragma unroll
        for (int off = 32; off; off >>= 1) sum += __shfl_xor(sum, off);
        float inv = 1.f / sum;
        f32x4 o0, o1;
        bf16x8 pk;
        #pragma unroll
        for (int e = 0; e < 4; ++e) {
            o0[e] = sc[e] * inv; o1[e] = sc[e + 4] * inv;
            pk[e]     = (short)f2bf(o0[e]);
            pk[e + 4] = (short)f2bf(o1[e]);
        }
        __builtin_nontemporal_store(o0, (f32x4*)&a4out[(size_t)row * VV + lane * 8]);
        __builtin_nontemporal_store(o1, (f32x4*)&a4out[(size_t)row * VV + lane * 8 + 4]);
        *(bf16x8*)&tile[il][lane * 8] = pk;
    }
    __syncthreads();

    // transposed write-out: a4t[n][w][i0..i0+31], 64 w-rows per pass, 8 passes
    int i4    = (threadIdx.x & 7) * 4;
    int wbase = threadIdx.x >> 3;         // 0..63
    unsigned short* dst = a4t + (size_t)n * VV * VV + i0;
    #pragma unroll
    for (int ws = 0; ws < 8; ++ws) {
        int w = ws * 64 + wbase;
        ushort4 val;
        val.x = tile[i4 + 0][w];
        val.y = tile[i4 + 1][w];
        val.z = tile[i4 + 2][w];
        val.w = tile[i4 + 3][w];
        *(ushort4*)&dst[(size_t)w * VV + i4] = val;
    }
}

// ---------------- k3: out[n,r,w] = sum_v xc[n,r,v] * a4t[n,w,v]   (MFMA bf16)
//   768 blocks x 256 threads (3/CU), tile M=64 N=128 BK=64, double-buffered,
//   octet-XOR swizzle, XCD swizzle, LDS-staged coalesced NT epilogue.
__global__ __launch_bounds__(256) void k3_gemm(const unsigned short* __restrict__ xcb,
                                               const unsigned short* __restrict__ a4t,
                                               float* __restrict__ outp) {
    __shared__ __align__(16) unsigned char lds_raw[49152];   // 48 KB: As dbuf | Bs dbuf; reused for out
#define ASP(bsel) ((unsigned short*)(lds_raw + (bsel) * 8192))
#define BSP(bsel) ((unsigned short*)(lds_raw + 16384 + (bsel) * 16384))

    // XCD-aware swizzle: 768 = 8 x 96, bijective; groups same-n blocks per XCD
    int bid = (blockIdx.x & 7) * 96 + (blockIdx.x >> 3);
    int n = bid / 24; int s = bid % 24; int rt = s >> 2, wt_ = s & 3;
    int r0 = rt * 64, w0 = wt_ * 128;
    int tid = threadIdx.x; int wv = tid >> 6, ln = tid & 63;
    int wr = wv >> 1, wc = wv & 1;        // wave tile: r in [wr*32,+32), w in [wc*64,+64)
    const unsigned short* Ag = xcb + (size_t)n * (COUTC * TT) * VV;
    const unsigned short* Bg = a4t + (size_t)n * VV * VV;

    int fr  = ln & 15;
    int fkq = ln >> 4;
    int st_row = tid >> 3;                // 0..31
    int st_g   = tid & 7;                 // 16B granule 0..7

    f32x4 acc[2][4] = {};

#define STAGE(bsel, kt) do {                                                          \
        int k0_ = (kt) * 64;                                                          \
        _Pragma("unroll")                                                             \
        for (int c2 = 0; c2 < 2; ++c2) {                                              \
            int row = c2 * 32 + st_row;                                               \
            GLD16(Ag + (size_t)(r0 + row) * VV + k0_ + ((st_g ^ (row & 7)) << 3),     \
                  &ASP(bsel)[c2 * 2048 + wv * 512]);                                  \
        }                                                                             \
        _Pragma("unroll")                                                             \
        for (int c4 = 0; c4 < 4; ++c4) {                                              \
            int row = c4 * 32 + st_row;                                               \
            GLD16(Bg + (size_t)(w0 + row) * VV + k0_ + ((st_g ^ (row & 7)) << 3),     \
                  &BSP(bsel)[c4 * 2048 + wv * 512]);                                  \
        }                                                                             \
    } while (0)

    STAGE(0, 0);
    __syncthreads();

    for (int kt = 0; kt < 8; ++kt) {
        int cur = kt & 1;
        if (kt < 7) STAGE(cur ^ 1, kt + 1);   // prefetch next K-tile into other buffer

        #pragma unroll
        for (int ks = 0; ks < 2; ++ks) {
            int g = ks * 4 + fkq;
            bf16x8 af[2], bfv[4];
            #pragma unroll
            for (int mi = 0; mi < 2; ++mi) {
                int r = wr * 32 + mi * 16 + fr;
                af[mi] = *(const bf16x8*)&ASP(cur)[r * 64 + ((g ^ (r & 7)) << 3)];
            }
            #pragma unroll
            for (int ni = 0; ni < 4; ++ni) {
                int w = wc * 64 + ni * 16 + fr;
                bfv[ni] = *(const bf16x8*)&BSP(cur)[w * 64 + ((g ^ (w & 7)) << 3)];
            }
            #pragma unroll
            for (int ni = 0; ni < 4; ++ni)
                #pragma unroll
                for (int mi = 0; mi < 2; ++mi)
                    acc[mi][ni] = __builtin_amdgcn_mfma_f32_16x16x32_bf16(af[mi], bfv[ni], acc[mi][ni], 0, 0, 0);
        }
        __syncthreads();
    }
#undef STAGE

    // ---- epilogue: acc -> LDS [64][132] f32 (conflict-free) -> coalesced NT f32x4 stores
    float* ot = (float*)lds_raw;          // 64*132*4 = 33.8 KB <= 48 KB
    #pragma unroll
    for (int mi = 0; mi < 2; ++mi) {
        int rbase = wr * 32 + mi * 16 + (ln >> 4) * 4;
        #pragma unroll
        for (int ni = 0; ni < 4; ++ni) {
            int col = wc * 64 + ni * 16 + (ln & 15);
            #pragma unroll
            for (int q = 0; q < 4; ++q)
                ot[(rbase + q) * 132 + col] = acc[mi][ni][q];
        }
    }
    __syncthreads();
    {
        float* og = outp + ((size_t)n * (COUTC * TT) + r0) * VV + w0;
        int orow = tid >> 5;              // 0..7
        int ogr  = tid & 31;              // 16B granule 0..31
        #pragma unroll
        for (int p = 0; p < 8; ++p) {
            int row = p * 8 + orow;
            f32x4 v = *(const f32x4*)&ot[row * 132 + ogr * 4];
            __builtin_nontemporal_store(v, (f32x4*)&og[(size_t)row * VV + ogr * 4]);
        }
    }
#undef ASP
#undef BSP
}

extern "C" void kernel_launch(void* const* d_in, const int* in_sizes, int n_in,
                              void* d_out, int out_size, void* d_ws, size_t ws_size,
                              hipStream_t stream) {
    const float* x      = (const float*)d_in[0];
    const float* A      = (const float*)d_in[1];
    const float* conv_w = (const float*)d_in[2];
    const float* conv_b = (const float*)d_in[3];
    const float* l1w    = (const float*)d_in[4];
    const float* l1b    = (const float*)d_in[5];
    const float* l2w    = (const float*)d_in[6];
    const float* l2b    = (const float*)d_in[7];

    float* outp  = (float*)d_out;                          // (N,COUT,T,V)
    float* a4out = outp + (size_t)BN * COUTC * TT * VV;    // (N,1,V,V)

    unsigned short* xcb = (unsigned short*)d_ws;                         // bf16 xc
    unsigned short* a4t = xcb + (size_t)BN * COUTC * TT * VV;            // bf16 a4^T [n][w][i]
    float* spartS = (float*)(a4t + (size_t)BN * VV * VV);                // [n][t][v]
    float* spartD = spartS + (size_t)BN * TT * VV;

    k1_conv    <<<BN * TT * 4, 256, 0, stream>>>(x, conv_w, conv_b, l1w, l2w, xcb, spartS, spartD);
    k2_softmax <<<BN * 16, 512, 0, stream>>>(A, spartS, spartD, l1w, l1b, l2b, a4out, a4t);
    k3_gemm    <<<BN * 24, 256, 0, stream>>>(xcb, a4t, outp);
}

// Round 9
// 46.479 us; speedup vs baseline: 1.2499x; 1.2499x over previous
//
#include <hip/hip_runtime.h>
#include <hip/hip_bf16.h>
#include <stdint.h>

#define BN 32
#define CIN 64
#define COUTC 64
#define TT 6
#define VV 512
#define NEG_FILL -1000.0f
#define SLOPE 0.2f

using bf16x8 = __attribute__((ext_vector_type(8))) short;
using bf16x4 = __attribute__((ext_vector_type(4))) short;
using f32x4  = __attribute__((ext_vector_type(4))) float;

static __device__ __forceinline__ unsigned short f2bf(float f) {
    union { float f; unsigned int i; } x; x.f = f;
    unsigned int r = x.i + 0x7FFFu + ((x.i >> 16) & 1u);
    return (unsigned short)(r >> 16);
}

#define GLD16(gp, lp) __builtin_amdgcn_global_load_lds( \
    (const __attribute__((address_space(1))) void*)(gp), \
    (__attribute__((address_space(3))) void*)(lp), 16, 0, 0)

// ---------------- k1: xc = W·x + b via MFMA (bf16 inputs, f32 accum)
//   (round-7 verbatim: plain cached loads/stores)
__global__ __launch_bounds__(256) void k1_conv(const float* __restrict__ x,
                                               const float* __restrict__ W,
                                               const float* __restrict__ bias,
                                               const float* __restrict__ l1w,
                                               const float* __restrict__ l2w,
                                               unsigned short* __restrict__ xcb,
                                               float* __restrict__ spartS,
                                               float* __restrict__ spartD) {
    __shared__ __align__(16) unsigned short Ws[64 * 64];    // 8 KB  [o][i] octet-swizzled
    __shared__ __align__(16) unsigned short Bs[128 * 64];   // 16 KB [v][i]; reused for out
    int bid = blockIdx.x;                  // (n*T + t)*4 + vq
    int vq = bid & 3; int nt = bid >> 2; int t = nt % TT; int n = nt / TT;
    int tid = threadIdx.x; int wv = tid >> 6, ln = tid & 63;
    int v0 = vq * 128;

    {
        int o = tid >> 2, i16 = (tid & 3) * 16;
        const float* wr_ = W + o * CIN + i16;
        f32x4 a = *(const f32x4*)&wr_[0], b = *(const f32x4*)&wr_[4];
        f32x4 c = *(const f32x4*)&wr_[8], d = *(const f32x4*)&wr_[12];
        bf16x8 p0, p1;
        #pragma unroll
        for (int e = 0; e < 4; ++e) {
            p0[e] = (short)f2bf(a[e]); p0[e + 4] = (short)f2bf(b[e]);
            p1[e] = (short)f2bf(c[e]); p1[e + 4] = (short)f2bf(d[e]);
        }
        int j0 = i16 >> 3;
        *(bf16x8*)&Ws[o * 64 + ((j0 ^ (o & 7)) << 3)]       = p0;
        *(bf16x8*)&Ws[o * 64 + (((j0 + 1) ^ (o & 7)) << 3)] = p1;
    }
    const float* xg = x + ((size_t)(n * CIN) * TT + t) * VV + v0;
    {
        int v4 = (tid & 31) * 4;
        int ig0 = tid >> 5;
        #pragma unroll
        for (int g = 0; g < 2; ++g) {
            int i4 = (ig0 + g * 8) * 4;
            f32x4 r0 = *(const f32x4*)&xg[(size_t)(i4 + 0) * TT * VV + v4];
            f32x4 r1 = *(const f32x4*)&xg[(size_t)(i4 + 1) * TT * VV + v4];
            f32x4 r2 = *(const f32x4*)&xg[(size_t)(i4 + 2) * TT * VV + v4];
            f32x4 r3 = *(const f32x4*)&xg[(size_t)(i4 + 3) * TT * VV + v4];
            int j = i4 >> 3, h = (i4 >> 2) & 1;
            #pragma unroll
            for (int c = 0; c < 4; ++c) {
                int v = v4 + c;
                bf16x4 col;
                col[0] = (short)f2bf(r0[c]); col[1] = (short)f2bf(r1[c]);
                col[2] = (short)f2bf(r2[c]); col[3] = (short)f2bf(r3[c]);
                *(bf16x4*)&Bs[v * 64 + ((j ^ (v & 7)) << 3) + h * 4] = col;
            }
        }
    }
    __syncthreads();

    int fr = ln & 15, fkq = ln >> 4;
    f32x4 acc[4][2] = {};
    #pragma unroll
    for (int ks = 0; ks < 2; ++ks) {
        bf16x8 af[4], bfv[2];
        int oct = fkq + ks * 4;
        #pragma unroll
        for (int mi = 0; mi < 4; ++mi) {
            int o = mi * 16 + fr;
            af[mi] = *(const bf16x8*)&Ws[o * 64 + ((oct ^ (o & 7)) << 3)];
        }
        #pragma unroll
        for (int ni = 0; ni < 2; ++ni) {
            int v = wv * 32 + ni * 16 + fr;
            bfv[ni] = *(const bf16x8*)&Bs[v * 64 + ((oct ^ (v & 7)) << 3)];
        }
        #pragma unroll
        for (int mi = 0; mi < 4; ++mi)
            #pragma unroll
            for (int ni = 0; ni < 2; ++ni)
                acc[mi][ni] = __builtin_amdgcn_mfma_f32_16x16x32_bf16(af[mi], bfv[ni], acc[mi][ni], 0, 0, 0);
    }
    __syncthreads();

    float l2wt = l2w[t];
    float partS[2] = {0.f, 0.f}, partD[2] = {0.f, 0.f};
    #pragma unroll
    for (int mi = 0; mi < 4; ++mi)
        #pragma unroll
        for (int q = 0; q < 4; ++q) {
            int o = mi * 16 + (ln >> 4) * 4 + q;
            float bv = bias[o];
            float wS = l1w[o], wD = l1w[COUTC + o];
            #pragma unroll
            for (int ni = 0; ni < 2; ++ni) {
                float z = acc[mi][ni][q] + bv;
                partS[ni] += wS * z;
                partD[ni] += wD * z;
                int vloc = wv * 32 + ni * 16 + fr;
                int vsw = (((vloc >> 3) ^ (o & 15)) << 3) | (vloc & 7);
                Bs[o * 128 + vsw] = f2bf(z);
            }
        }
    #pragma unroll
    for (int ni = 0; ni < 2; ++ni) {
        float sS = partS[ni], sD = partD[ni];
        sS += __shfl_xor(sS, 16); sS += __shfl_xor(sS, 32);
        sD += __shfl_xor(sD, 16); sD += __shfl_xor(sD, 32);
        if (ln < 16) {
            int v = v0 + wv * 32 + ni * 16 + ln;
            size_t si_ = ((size_t)n * TT + t) * VV + v;
            spartS[si_] = l2wt * sS;
            spartD[si_] = l2wt * sD;
        }
    }
    __syncthreads();

    {
        int o = tid >> 2, c32 = (tid & 3) * 32;
        size_t base = ((size_t)(n * COUTC + o) * TT + t) * VV + v0 + c32;
        #pragma unroll
        for (int q = 0; q < 4; ++q) {
            int oct = (tid & 3) * 4 + q;
            bf16x8 val = *(const bf16x8*)&Bs[o * 128 + ((oct ^ (o & 15)) << 3)];
            *(bf16x8*)&xcb[base + q * 8] = val;
        }
    }
}

// ---------------- k2: softmax rows -> a4 f32 (d_out) + fused LDS transpose -> a4t bf16
//   (round-7 verbatim: plain cached loads/stores)
__global__ __launch_bounds__(512) void k2_softmax(const float* __restrict__ A,
                                                  const float* __restrict__ spartS,
                                                  const float* __restrict__ spartD,
                                                  const float* __restrict__ l1w,
                                                  const float* __restrict__ l1b_,
                                                  const float* __restrict__ l2b_,
                                                  float* __restrict__ a4out,
                                                  unsigned short* __restrict__ a4t) {
    __shared__ unsigned short tile[32][520];   // 32 rows x 512 (+8 pad), 32.5 KB
    __shared__ float si_loc[32];
    int blk = blockIdx.x;                 // n*16 + ib
    int n = blk >> 4; int i0 = (blk & 15) * 32;
    int wv = threadIdx.x >> 6, lane = threadIdx.x & 63;

    float sws = 0.f, swd = 0.f;
    for (int c = 0; c < COUTC; ++c) { sws += l1w[c]; swd += l1w[COUTC + c]; }
    float l2b = l2b_[0], l1b = l1b_[0];

    if (threadIdx.x < 32) {
        float s = 0.f;
        #pragma unroll
        for (int t = 0; t < TT; ++t)
            s += spartS[((size_t)n * TT + t) * VV + i0 + threadIdx.x];
        si_loc[threadIdx.x] = s + l2b * sws;
    }
    f32x4 sj0 = {0.f, 0.f, 0.f, 0.f}, sj1 = {0.f, 0.f, 0.f, 0.f};
    #pragma unroll
    for (int t = 0; t < TT; ++t) {
        const float* p = &spartD[((size_t)n * TT + t) * VV + lane * 8];
        f32x4 d0 = *(const f32x4*)&p[0];
        f32x4 d1 = *(const f32x4*)&p[4];
        #pragma unroll
        for (int e = 0; e < 4; ++e) { sj0[e] += d0[e]; sj1[e] += d1[e]; }
    }
    float cst = l2b * swd + l1b;
    #pragma unroll
    for (int e = 0; e < 4; ++e) { sj0[e] += cst; sj1[e] += cst; }
    __syncthreads();

    for (int it = 0; it < 4; ++it) {
        int il = it * 8 + wv;             // local row 0..31
        int i  = i0 + il;
        int row = n * VV + i;
        float s_i = si_loc[il];
        const float* mrow = A + ((size_t)n * 8 + 7) * VV * VV + (size_t)i * VV;
        f32x4 m0 = *(const f32x4*)&mrow[lane * 8];
        f32x4 m1 = *(const f32x4*)&mrow[lane * 8 + 4];

        float sc[8];
        float mx = -1e30f;
        #pragma unroll
        for (int e = 0; e < 8; ++e) {
            float mk = (e < 4) ? m0[e] : m1[e - 4];
            float s  = s_i + ((e < 4) ? sj0[e] : sj1[e - 4]);
            s = (s >= 0.f) ? s : SLOPE * s;
            s = (mk == 0.f) ? NEG_FILL : s;
            sc[e] = s;
            mx = fmaxf(mx, s);
        }
        #pragma unroll
        for (int off = 32; off; off >>= 1) mx = fmaxf(mx, __shfl_xor(mx, off));
        float sum = 0.f;
        #pragma unroll
        for (int e = 0; e < 8; ++e) { sc[e] = __expf(sc[e] - mx); sum += sc[e]; }
        #pragma unroll
        for (int off = 32; off; off >>= 1) sum += __shfl_xor(sum, off);
        float inv = 1.f / sum;
        f32x4 o0, o1;
        bf16x8 pk;
        #pragma unroll
        for (int e = 0; e < 4; ++e) {
            o0[e] = sc[e] * inv; o1[e] = sc[e + 4] * inv;
            pk[e]     = (short)f2bf(o0[e]);
            pk[e + 4] = (short)f2bf(o1[e]);
        }
        *(f32x4*)&a4out[(size_t)row * VV + lane * 8]     = o0;
        *(f32x4*)&a4out[(size_t)row * VV + lane * 8 + 4] = o1;
        *(bf16x8*)&tile[il][lane * 8] = pk;
    }
    __syncthreads();

    // transposed write-out: a4t[n][w][i0..i0+31], 64 w-rows per pass, 8 passes
    int i4    = (threadIdx.x & 7) * 4;
    int wbase = threadIdx.x >> 3;         // 0..63
    unsigned short* dst = a4t + (size_t)n * VV * VV + i0;
    #pragma unroll
    for (int ws = 0; ws < 8; ++ws) {
        int w = ws * 64 + wbase;
        ushort4 val;
        val.x = tile[i4 + 0][w];
        val.y = tile[i4 + 1][w];
        val.z = tile[i4 + 2][w];
        val.w = tile[i4 + 3][w];
        *(ushort4*)&dst[(size_t)w * VV + i4] = val;
    }
}

// ---------------- k3: out[n,r,w] = sum_v xc[n,r,v] * a4t[n,w,v]   (MFMA bf16)
//   768 blocks x 256 threads (3/CU), tile M=64 N=128 BK=64, double-buffered,
//   octet-XOR swizzle, XCD swizzle. Epilogue: LDS-staged coalesced f32x4
//   stores (CACHED — NT was the round-8 regression).
__global__ __launch_bounds__(256) void k3_gemm(const unsigned short* __restrict__ xcb,
                                               const unsigned short* __restrict__ a4t,
                                               float* __restrict__ outp) {
    __shared__ __align__(16) unsigned char lds_raw[49152];   // 48 KB: As dbuf | Bs dbuf; reused for out
#define ASP(bsel) ((unsigned short*)(lds_raw + (bsel) * 8192))
#define BSP(bsel) ((unsigned short*)(lds_raw + 16384 + (bsel) * 16384))

    // XCD-aware swizzle: 768 = 8 x 96, bijective; groups same-n blocks per XCD
    int bid = (blockIdx.x & 7) * 96 + (blockIdx.x >> 3);
    int n = bid / 24; int s = bid % 24; int rt = s >> 2, wt_ = s & 3;
    int r0 = rt * 64, w0 = wt_ * 128;
    int tid = threadIdx.x; int wv = tid >> 6, ln = tid & 63;
    int wr = wv >> 1, wc = wv & 1;        // wave tile: r in [wr*32,+32), w in [wc*64,+64)
    const unsigned short* Ag = xcb + (size_t)n * (COUTC * TT) * VV;
    const unsigned short* Bg = a4t + (size_t)n * VV * VV;

    int fr  = ln & 15;
    int fkq = ln >> 4;
    int st_row = tid >> 3;                // 0..31
    int st_g   = tid & 7;                 // 16B granule 0..7

    f32x4 acc[2][4] = {};

#define STAGE(bsel, kt) do {                                                          \
        int k0_ = (kt) * 64;                                                          \
        _Pragma("unroll")                                                             \
        for (int c2 = 0; c2 < 2; ++c2) {                                              \
            int row = c2 * 32 + st_row;                                               \
            GLD16(Ag + (size_t)(r0 + row) * VV + k0_ + ((st_g ^ (row & 7)) << 3),     \
                  &ASP(bsel)[c2 * 2048 + wv * 512]);                                  \
        }                                                                             \
        _Pragma("unroll")                                                             \
        for (int c4 = 0; c4 < 4; ++c4) {                                              \
            int row = c4 * 32 + st_row;                                               \
            GLD16(Bg + (size_t)(w0 + row) * VV + k0_ + ((st_g ^ (row & 7)) << 3),     \
                  &BSP(bsel)[c4 * 2048 + wv * 512]);                                  \
        }                                                                             \
    } while (0)

    STAGE(0, 0);
    __syncthreads();

    for (int kt = 0; kt < 8; ++kt) {
        int cur = kt & 1;
        if (kt < 7) STAGE(cur ^ 1, kt + 1);   // prefetch next K-tile into other buffer

        #pragma unroll
        for (int ks = 0; ks < 2; ++ks) {
            int g = ks * 4 + fkq;
            bf16x8 af[2], bfv[4];
            #pragma unroll
            for (int mi = 0; mi < 2; ++mi) {
                int r = wr * 32 + mi * 16 + fr;
                af[mi] = *(const bf16x8*)&ASP(cur)[r * 64 + ((g ^ (r & 7)) << 3)];
            }
            #pragma unroll
            for (int ni = 0; ni < 4; ++ni) {
                int w = wc * 64 + ni * 16 + fr;
                bfv[ni] = *(const bf16x8*)&BSP(cur)[w * 64 + ((g ^ (w & 7)) << 3)];
            }
            #pragma unroll
            for (int ni = 0; ni < 4; ++ni)
                #pragma unroll
                for (int mi = 0; mi < 2; ++mi)
                    acc[mi][ni] = __builtin_amdgcn_mfma_f32_16x16x32_bf16(af[mi], bfv[ni], acc[mi][ni], 0, 0, 0);
        }
        __syncthreads();
    }
#undef STAGE

    // ---- epilogue: acc -> LDS [64][132] f32 (conflict-free) -> coalesced f32x4 stores
    float* ot = (float*)lds_raw;          // 64*132*4 = 33.8 KB <= 48 KB
    #pragma unroll
    for (int mi = 0; mi < 2; ++mi) {
        int rbase = wr * 32 + mi * 16 + (ln >> 4) * 4;
        #pragma unroll
        for (int ni = 0; ni < 4; ++ni) {
            int col = wc * 64 + ni * 16 + (ln & 15);
            #pragma unroll
            for (int q = 0; q < 4; ++q)
                ot[(rbase + q) * 132 + col] = acc[mi][ni][q];
        }
    }
    __syncthreads();
    {
        float* og = outp + ((size_t)n * (COUTC * TT) + r0) * VV + w0;
        int orow = tid >> 5;              // 0..7
        int ogr  = tid & 31;              // 16B granule 0..31
        #pragma unroll
        for (int p = 0; p < 8; ++p) {
            int row = p * 8 + orow;
            f32x4 v = *(const f32x4*)&ot[row * 132 + ogr * 4];
            *(f32x4*)&og[(size_t)row * VV + ogr * 4] = v;
        }
    }
#undef ASP
#undef BSP
}

extern "C" void kernel_launch(void* const* d_in, const int* in_sizes, int n_in,
                              void* d_out, int out_size, void* d_ws, size_t ws_size,
                              hipStream_t stream) {
    const float* x      = (const float*)d_in[0];
    const float* A      = (const float*)d_in[1];
    const float* conv_w = (const float*)d_in[2];
    const float* conv_b = (const float*)d_in[3];
    const float* l1w    = (const float*)d_in[4];
    const float* l1b    = (const float*)d_in[5];
    const float* l2w    = (const float*)d_in[6];
    const float* l2b    = (const float*)d_in[7];

    float* outp  = (float*)d_out;                          // (N,COUT,T,V)
    float* a4out = outp + (size_t)BN * COUTC * TT * VV;    // (N,1,V,V)

    unsigned short* xcb = (unsigned short*)d_ws;                         // bf16 xc
    unsigned short* a4t = xcb + (size_t)BN * COUTC * TT * VV;            // bf16 a4^T [n][w][i]
    float* spartS = (float*)(a4t + (size_t)BN * VV * VV);                // [n][t][v]
    float* spartD = spartS + (size_t)BN * TT * VV;

    k1_conv    <<<BN * TT * 4, 256, 0, stream>>>(x, conv_w, conv_b, l1w, l2w, xcb, spartS, spartD);
    k2_softmax <<<BN * 16, 512, 0, stream>>>(A, spartS, spartD, l1w, l1b, l2b, a4out, a4t);
    k3_gemm    <<<BN * 24, 256, 0, stream>>>(xcb, a4t, outp);
}